// Round 1
// baseline (1421.369 us; speedup 1.0000x reference)
//
#include <hip/hip_runtime.h>
#include <math.h>

// Sizes fixed by the problem
// B=512, C=256, H=W=14 -> L=196, D=512

__device__ __forceinline__ float wsum(float v) {
#pragma unroll
  for (int o = 32; o > 0; o >>= 1) v += __shfl_xor(v, o, 64);
  return v;
}
__device__ __forceinline__ float wmax(float v) {
#pragma unroll
  for (int o = 32; o > 0; o >>= 1) v = fmaxf(v, __shfl_xor(v, o, 64));
  return v;
}

// ---------------- Kernel 1: similarity weights -----------------------------
// simw[b][l] = cross_attn(b) * sigmoid(imf_n . W_sim[l] + b_sim[l]) / 10
__global__ __launch_bounds__(256) void k_simw(const float* __restrict__ img,
                                              const float* __restrict__ txt,
                                              const float* __restrict__ Wsim,
                                              const float* __restrict__ bsim,
                                              float* __restrict__ simw) {
  const int b = blockIdx.x, tid = threadIdx.x, lane = tid & 63, wv = tid >> 6;
  __shared__ float s_img[512];
  __shared__ float s_part[3][4];

  float i0 = img[b * 512 + tid], i1 = img[b * 512 + 256 + tid];
  float t0 = txt[b * 512 + tid], t1 = txt[b * 512 + 256 + tid];
  float ssi = wsum(i0 * i0 + i1 * i1);
  float sst = wsum(t0 * t0 + t1 * t1);
  float dd = wsum(i0 * t0 + i1 * t1);
  if (lane == 0) { s_part[0][wv] = ssi; s_part[1][wv] = sst; s_part[2][wv] = dd; }
  __syncthreads();
  float ni = fmaxf(sqrtf(s_part[0][0] + s_part[0][1] + s_part[0][2] + s_part[0][3]), 1e-12f);
  float nt = fmaxf(sqrtf(s_part[1][0] + s_part[1][1] + s_part[1][2] + s_part[1][3]), 1e-12f);
  float dot = s_part[2][0] + s_part[2][1] + s_part[2][2] + s_part[2][3];
  float cross = dot / (ni * nt);
  float rni = 1.0f / ni;
  s_img[tid] = i0 * rni;
  s_img[tid + 256] = i1 * rni;
  __syncthreads();

  // wave wv handles l = wv, wv+4, ... ; lanes split the 512-d dot (coalesced)
  for (int l = wv; l < 196; l += 4) {
    const float* wr = Wsim + (size_t)l * 512;
    float p = 0.f;
#pragma unroll
    for (int k = 0; k < 8; ++k) p = fmaf(s_img[lane + 64 * k], wr[lane + 64 * k], p);
    p = wsum(p);
    if (lane == 0) {
      float z = p + bsim[l];
      float sg = 1.0f / (1.0f + __expf(-z));
      simw[b * 196 + l] = cross * sg * 0.1f;
    }
  }
}

// ---------------- Kernel 2: fused spatial self-attention -------------------
// One block per batch. Flash-style: pass A computes softmax row stats,
// pass B recomputes score columns, forms attn^T chunks in LDS, does the
// weighted GEMM and writes guide = (sam + weighted)*0.5*simw to out.
__global__ __launch_bounds__(256) void k_attn(const float* __restrict__ sam,
                                              const float* __restrict__ simw,
                                              float* __restrict__ out) {
  const int b = blockIdx.x;
  const int tid = threadIdx.x, lane = tid & 63, wv = tid >> 6;
  const float* __restrict__ S = sam + (size_t)b * (256 * 196);
  float* __restrict__ O = out + (size_t)b * (256 * 196);
  const float* __restrict__ SW = simw + b * 196;

  __shared__ float s_inv[196];   // 1/max(||col||,eps)
  __shared__ float s_max[196];   // softmax row max
  __shared__ float s_rsum[196];  // 1/sumexp
  __shared__ float bufS[28 * 197];  // score chunk (pass A) / attn^T chunk (pass B)
  __shared__ float bufT[256 * 29];  // c-tile staging (32x197 fits) / samLT (256x28)

  // ---- column inverse norms (coalesced across threads) ----
  for (int l = tid; l < 196; l += 256) {
    float ss = 0.f;
    for (int c = 0; c < 256; ++c) {
      float v = S[c * 196 + l];
      ss = fmaf(v, v, ss);
    }
    s_inv[l] = 1.0f / fmaxf(sqrtf(ss), 1e-12f);
  }

  // ---- Pass A: row-chunked scores -> softmax stats only ----
  for (int r0 = 0; r0 < 196; r0 += 28) {
    float acc[7][4];
#pragma unroll
    for (int i = 0; i < 7; ++i)
#pragma unroll
      for (int j = 0; j < 4; ++j) acc[i][j] = 0.f;
    const int lr = r0 + wv * 7;  // this wave's first row
    for (int ct = 0; ct < 8; ++ct) {
      __syncthreads();
      for (int i = tid; i < 32 * 196; i += 256)
        bufT[(i / 196) * 197 + (i % 196)] = S[ct * 32 * 196 + i];
      __syncthreads();
#pragma unroll 2
      for (int c = 0; c < 32; ++c) {
        const float* row = bufT + c * 197;
        float a[7];
#pragma unroll
        for (int i = 0; i < 7; ++i) a[i] = row[lr + i];  // wave-broadcast
        float b0 = row[lane], b1 = row[lane + 64], b2 = row[lane + 128];
        float b3 = row[lane + 192];  // garbage for lane>=4 is masked at write
#pragma unroll
        for (int i = 0; i < 7; ++i) {
          acc[i][0] = fmaf(a[i], b0, acc[i][0]);
          acc[i][1] = fmaf(a[i], b1, acc[i][1]);
          acc[i][2] = fmaf(a[i], b2, acc[i][2]);
          acc[i][3] = fmaf(a[i], b3, acc[i][3]);
        }
      }
    }
    // scale & store scores in LDS
#pragma unroll
    for (int j = 0; j < 4; ++j) {
      int m = lane + 64 * j;
      if (m < 196) {
        float im = s_inv[m] * 0.0625f;  // /sqrt(256)
#pragma unroll
        for (int i = 0; i < 7; ++i)
          bufS[(wv * 7 + i) * 197 + m] = acc[i][j] * s_inv[lr + i] * im;
      }
    }
    __syncthreads();
    // per-row softmax stats (wave-parallel over its 7 rows)
#pragma unroll
    for (int i = 0; i < 7; ++i) {
      const int rl = wv * 7 + i;
      const float* sr = bufS + rl * 197;
      float v0 = sr[lane], v1 = sr[lane + 64], v2 = sr[lane + 128];
      bool g = (lane + 192) < 196;
      float v3 = g ? sr[lane + 192] : -1e30f;
      float mx = wmax(fmaxf(fmaxf(v0, v1), fmaxf(v2, v3)));
      float sm = __expf(v0 - mx) + __expf(v1 - mx) + __expf(v2 - mx) +
                 (g ? __expf(v3 - mx) : 0.f);
      sm = wsum(sm);
      if (lane == 0) { s_max[r0 + rl] = mx; s_rsum[r0 + rl] = 1.0f / sm; }
    }
  }
  __syncthreads();

  // ---- Pass B: per 28-column chunk: recompute scores -> attn^T -> weighted ----
  const int cg = tid >> 2, tq = tid & 3;
  for (int m0 = 0; m0 < 196; m0 += 28) {
    float acc[7][4];
#pragma unroll
    for (int i = 0; i < 7; ++i)
#pragma unroll
      for (int j = 0; j < 4; ++j) acc[i][j] = 0.f;
    const int mg = m0 + wv * 7;  // this wave's first output column m
    for (int ct = 0; ct < 8; ++ct) {
      __syncthreads();
      for (int i = tid; i < 32 * 196; i += 256)
        bufT[(i / 196) * 197 + (i % 196)] = S[ct * 32 * 196 + i];
      __syncthreads();
#pragma unroll 2
      for (int c = 0; c < 32; ++c) {
        const float* row = bufT + c * 197;
        float a[7];
#pragma unroll
        for (int i = 0; i < 7; ++i) a[i] = row[mg + i];
        float b0 = row[lane], b1 = row[lane + 64], b2 = row[lane + 128];
        float b3 = row[lane + 192];
#pragma unroll
        for (int i = 0; i < 7; ++i) {
          acc[i][0] = fmaf(a[i], b0, acc[i][0]);
          acc[i][1] = fmaf(a[i], b1, acc[i][1]);
          acc[i][2] = fmaf(a[i], b2, acc[i][2]);
          acc[i][3] = fmaf(a[i], b3, acc[i][3]);
        }
      }
    }
    __syncthreads();
    // attn^T[mc][l] = exp(score - rowmax[l]) * rsum[l]
#pragma unroll
    for (int j = 0; j < 4; ++j) {
      int l = lane + 64 * j;
      if (l < 196) {
        float il = s_inv[l] * 0.0625f;
        float mxl = s_max[l], rsl = s_rsum[l];
#pragma unroll
        for (int i = 0; i < 7; ++i) {
          float sc = acc[i][j] * s_inv[mg + i] * il;
          bufS[(wv * 7 + i) * 197 + l] = __expf(sc - mxl) * rsl;
        }
      }
    }
    __syncthreads();
    // weighted[c, m0+mc] = sum_l S[c,l] * attnT[mc][l] ; 4x7 register tiles
    float w[4][7];
#pragma unroll
    for (int ii = 0; ii < 4; ++ii)
#pragma unroll
      for (int i = 0; i < 7; ++i) w[ii][i] = 0.f;
    for (int lt = 0; lt < 7; ++lt) {
      __syncthreads();
      for (int i = tid; i < 256 * 28; i += 256) {
        int c = i / 28, j = i - c * 28;
        bufT[c * 29 + j] = S[c * 196 + lt * 28 + j];
      }
      __syncthreads();
#pragma unroll 4
      for (int j = 0; j < 28; ++j) {
        float a0 = bufT[(cg * 4 + 0) * 29 + j];
        float a1 = bufT[(cg * 4 + 1) * 29 + j];
        float a2 = bufT[(cg * 4 + 2) * 29 + j];
        float a3 = bufT[(cg * 4 + 3) * 29 + j];
#pragma unroll
        for (int i = 0; i < 7; ++i) {
          float bv = bufS[(tq * 7 + i) * 197 + lt * 28 + j];
          w[0][i] = fmaf(a0, bv, w[0][i]);
          w[1][i] = fmaf(a1, bv, w[1][i]);
          w[2][i] = fmaf(a2, bv, w[2][i]);
          w[3][i] = fmaf(a3, bv, w[3][i]);
        }
      }
    }
    // epilogue: guide = (sam + weighted) * 0.5 * simw[m]
#pragma unroll
    for (int i = 0; i < 7; ++i) {
      const int m = m0 + tq * 7 + i;
      float sw = SW[m] * 0.5f;
#pragma unroll
      for (int ii = 0; ii < 4; ++ii) {
        const int c = cg * 4 + ii;
        O[c * 196 + m] = (S[c * 196 + m] + w[ii][i]) * sw;
      }
    }
  }
}

// ---------------- Kernel 3: hierarchical norm (in-place on d_out) ----------
__global__ __launch_bounds__(256) void k_norm(float* __restrict__ x) {
  const int b = blockIdx.x, tid = threadIdx.x;
  float* __restrict__ X = x + (size_t)b * (256 * 196);
  __shared__ float s_mu[196], s_rs[196];
  __shared__ float s_rm[256], s_rc[256];
  __shared__ float tile[256 * 29];

  // channel LayerNorm stats per spatial position m (biased var, eps inside sqrt)
  if (tid < 196) {
    float s = 0.f, q = 0.f;
    for (int c = 0; c < 256; ++c) {
      float v = X[c * 196 + tid];
      s += v;
      q = fmaf(v, v, q);
    }
    float mu = s * (1.0f / 256.0f);
    float var = q * (1.0f / 256.0f) - mu * mu;
    s_mu[tid] = mu;
    s_rs[tid] = rsqrtf(fmaxf(var, 0.f) + 1e-5f);
  }
  __syncthreads();

  // spatial stats per channel row c of the channel-normalized values
  float rs = 0.f, rq = 0.f;
  for (int m0 = 0; m0 < 196; m0 += 28) {
    __syncthreads();
    for (int i = tid; i < 256 * 28; i += 256) {
      int c = i / 28, j = i - c * 28;
      tile[c * 29 + j] = X[c * 196 + m0 + j];
    }
    __syncthreads();
#pragma unroll
    for (int j = 0; j < 28; ++j) {
      float y = (tile[tid * 29 + j] - s_mu[m0 + j]) * s_rs[m0 + j];
      rs += y;
      rq = fmaf(y, y, rq);
    }
  }
  float rm = rs * (1.0f / 196.0f);
  float var = (rq - 196.0f * rm * rm) * (1.0f / 195.0f);  // Bessel
  float sd = sqrtf(fmaxf(var, 0.f));
  s_rm[tid] = rm;
  s_rc[tid] = 1.0f / (sd + 1e-6f);  // eps added to STD per torch .std()
  __syncthreads();

  for (int i = tid; i < 256 * 196; i += 256) {
    int c = i / 196, m = i - c * 196;
    float y = (X[i] - s_mu[m]) * s_rs[m];
    X[i] = (y - s_rm[c]) * s_rc[c];
  }
}

extern "C" void kernel_launch(void* const* d_in, const int* in_sizes, int n_in,
                              void* d_out, int out_size, void* d_ws, size_t ws_size,
                              hipStream_t stream) {
  const float* img = (const float*)d_in[0];
  const float* txt = (const float*)d_in[1];
  const float* sam = (const float*)d_in[2];
  const float* Wsim = (const float*)d_in[3];
  const float* bsim = (const float*)d_in[4];
  float* out = (float*)d_out;
  float* simw = (float*)d_ws;  // B*196 floats = 401 KB

  const int B = in_sizes[0] / 512;  // 512

  k_simw<<<B, 256, 0, stream>>>(img, txt, Wsim, bsim, simw);
  k_attn<<<B, 256, 0, stream>>>(sam, simw, out);
  k_norm<<<B, 256, 0, stream>>>(out);
}

// Round 2
// 818.711 us; speedup vs baseline: 1.7361x; 1.7361x over previous
//
#include <hip/hip_runtime.h>
#include <math.h>

// B=512, C=256, H=W=14 -> L=196 (pad 208 rows / 224 K), D=512

typedef float f32x4 __attribute__((ext_vector_type(4)));
typedef short s16x8 __attribute__((ext_vector_type(8)));
typedef unsigned short ushort_t;

__device__ __forceinline__ float wsum(float v) {
#pragma unroll
  for (int o = 32; o > 0; o >>= 1) v += __shfl_xor(v, o, 64);
  return v;
}

__device__ __forceinline__ unsigned short f2bf(float f) {
  unsigned int u = __float_as_uint(f);
  u += 0x7FFFu + ((u >> 16) & 1u);  // RNE
  return (unsigned short)(u >> 16);
}

// ---------------- Kernel: similarity weights -------------------------------
__global__ __launch_bounds__(256) void k_simw(const float* __restrict__ img,
                                              const float* __restrict__ txt,
                                              const float* __restrict__ Wsim,
                                              const float* __restrict__ bsim,
                                              float* __restrict__ simw) {
  const int b = blockIdx.x, tid = threadIdx.x, lane = tid & 63, wv = tid >> 6;
  __shared__ float s_img[512];
  __shared__ float s_part[3][4];

  float i0 = img[b * 512 + tid], i1 = img[b * 512 + 256 + tid];
  float t0 = txt[b * 512 + tid], t1 = txt[b * 512 + 256 + tid];
  float ssi = wsum(i0 * i0 + i1 * i1);
  float sst = wsum(t0 * t0 + t1 * t1);
  float dd = wsum(i0 * t0 + i1 * t1);
  if (lane == 0) { s_part[0][wv] = ssi; s_part[1][wv] = sst; s_part[2][wv] = dd; }
  __syncthreads();
  float ni = fmaxf(sqrtf(s_part[0][0] + s_part[0][1] + s_part[0][2] + s_part[0][3]), 1e-12f);
  float nt = fmaxf(sqrtf(s_part[1][0] + s_part[1][1] + s_part[1][2] + s_part[1][3]), 1e-12f);
  float dot = s_part[2][0] + s_part[2][1] + s_part[2][2] + s_part[2][3];
  float cross = dot / (ni * nt);
  float rni = 1.0f / ni;
  s_img[tid] = i0 * rni;
  s_img[tid + 256] = i1 * rni;
  __syncthreads();

  for (int l = wv; l < 196; l += 4) {
    const float* wr = Wsim + (size_t)l * 512;
    float p = 0.f;
#pragma unroll
    for (int k = 0; k < 8; ++k) p = fmaf(s_img[lane + 64 * k], wr[lane + 64 * k], p);
    p = wsum(p);
    if (lane == 0) {
      float z = p + bsim[l];
      float sg = 1.0f / (1.0f + __expf(-z));
      simw[b * 196 + l] = cross * sg * 0.1f;
    }
  }
}

// ---------------- Kernel: prep — normalized transposed bf16 samnT ----------
// samnT[b][l][c] = sam[b][c][l] / max(||col l||, eps), rows l=196..207 zero.
__global__ __launch_bounds__(256) void k_prep(const float* __restrict__ sam,
                                              unsigned short* __restrict__ samnT) {
  const int b = blockIdx.x, tid = threadIdx.x, lane = tid & 63, wv = tid >> 6;
  const float* __restrict__ S = sam + (size_t)b * 50176;
  unsigned short* __restrict__ NT = samnT + (size_t)b * (208 * 256);
  __shared__ float s_inv[196];
  __shared__ float T[64 * 197];

  if (tid < 196) {
    float ss = 0.f;
    for (int c = 0; c < 256; ++c) {
      float v = S[c * 196 + tid];
      ss = fmaf(v, v, ss);
    }
    s_inv[tid] = 1.0f / fmaxf(sqrtf(ss), 1e-12f);
  }
  // zero pad rows l=196..207 (12*256 ushort = 1536 dwords)
  for (int i = tid; i < 1536; i += 256) ((unsigned int*)(NT + 196 * 256))[i] = 0;
  __syncthreads();

  for (int c0 = 0; c0 < 256; c0 += 64) {
    for (int cr = wv; cr < 64; cr += 4) {
      const float* Sr = S + (c0 + cr) * 196;
      float* Tr = T + cr * 197;
      Tr[lane] = Sr[lane] * s_inv[lane];
      Tr[lane + 64] = Sr[lane + 64] * s_inv[lane + 64];
      Tr[lane + 128] = Sr[lane + 128] * s_inv[lane + 128];
      if (lane < 4) Tr[lane + 192] = Sr[lane + 192] * s_inv[lane + 192];
    }
    __syncthreads();
    const int lrow = tid >> 3, cch = tid & 7;
    for (int l0 = 0; l0 < 196; l0 += 32) {
      int l = l0 + lrow;
      if (l < 196) {
        const float* Tc = T + (cch * 8) * 197 + l;
        unsigned short r[8];
#pragma unroll
        for (int k = 0; k < 8; ++k) r[k] = f2bf(Tc[k * 197]);
        uint4 o;
        o.x = r[0] | ((unsigned int)r[1] << 16);
        o.y = r[2] | ((unsigned int)r[3] << 16);
        o.z = r[4] | ((unsigned int)r[5] << 16);
        o.w = r[6] | ((unsigned int)r[7] << 16);
        *(uint4*)(NT + l * 256 + c0 + cch * 8) = o;
      }
    }
    __syncthreads();
  }
}

// ---------------- Kernel: scores GEMM + softmax -> attnT bf16 --------------
// One block per batch. Wave owns 2 row-strips of 16; full score rows live in
// registers; softmax stats via in-quad shfl; writes attnT[m][l] directly.
__device__ __forceinline__ void proc_strip(int s, f32x4* sc, unsigned short* AT,
                                           int quad, int l15) {
  const bool mval12 = (192 + l15) < 196;  // j==12 column validity
  float mx[4], rs[4];
#pragma unroll
  for (int r = 0; r < 4; ++r) {
    float m = -3e38f;
#pragma unroll
    for (int j = 0; j < 13; ++j) {
      float v = sc[j][r];
      if (j == 12 && !mval12) v = -3e38f;
      m = fmaxf(m, v);
    }
#pragma unroll
    for (int o = 1; o < 16; o <<= 1) m = fmaxf(m, __shfl_xor(m, o, 64));
    float s_ = 0.f;
#pragma unroll
    for (int j = 0; j < 13; ++j) {
      float e = __expf(sc[j][r] - m);
      if (j == 12 && !mval12) e = 0.f;
      s_ += e;
    }
#pragma unroll
    for (int o = 1; o < 16; o <<= 1) s_ += __shfl_xor(s_, o, 64);
    mx[r] = m;
    rs[r] = 1.0f / s_;
  }
  const int lb = s * 16 + quad * 4;
#pragma unroll
  for (int j = 0; j < 13; ++j) {
    unsigned short u[4];
#pragma unroll
    for (int r = 0; r < 4; ++r) {
      float a = __expf(sc[j][r] - mx[r]) * rs[r];
      if (lb + r >= 196) a = 0.f;  // K-padding rows of attn must be zero
      u[r] = f2bf(a);
    }
    uint2 o2;
    o2.x = u[0] | ((unsigned int)u[1] << 16);
    o2.y = u[2] | ((unsigned int)u[3] << 16);
    *(uint2*)(AT + (j * 16 + l15) * 224 + lb) = o2;
  }
}

__global__ __launch_bounds__(256, 2) void k_scores(const unsigned short* __restrict__ samnT,
                                                   unsigned short* __restrict__ attnT) {
  const int b = blockIdx.x, tid = threadIdx.x, lane = tid & 63, wv = tid >> 6;
  const int quad = lane >> 4, l15 = lane & 15;
  const unsigned short* __restrict__ NT = samnT + (size_t)b * (208 * 256);
  unsigned short* __restrict__ AT = attnT + (size_t)b * (208 * 224);

  // zero attnT[:, 208..223]
  for (int i = tid; i < 208 * 8; i += 256) {
    int m = i >> 3, k = i & 7;
    ((unsigned int*)(AT + m * 224 + 208))[k] = 0;
  }

  for (int p = wv; p < 7; p += 4) {
    const int s0 = 2 * p, s1 = (2 * p + 1 < 13) ? (2 * p + 1) : 12;
    s16x8 A0[8], A1[8];
#pragma unroll
    for (int ct = 0; ct < 8; ++ct) {
      A0[ct] = *(const s16x8*)(NT + (s0 * 16 + l15) * 256 + ct * 32 + quad * 8);
      A1[ct] = *(const s16x8*)(NT + (s1 * 16 + l15) * 256 + ct * 32 + quad * 8);
    }
    f32x4 sc0[13], sc1[13];
    const f32x4 z = {0.f, 0.f, 0.f, 0.f};
#pragma unroll
    for (int j = 0; j < 13; ++j) { sc0[j] = z; sc1[j] = z; }
#pragma unroll
    for (int j = 0; j < 13; ++j) {
#pragma unroll
      for (int ct = 0; ct < 8; ++ct) {
        s16x8 Bf = *(const s16x8*)(NT + (j * 16 + l15) * 256 + ct * 32 + quad * 8);
        sc0[j] = __builtin_amdgcn_mfma_f32_16x16x32_bf16(A0[ct], Bf, sc0[j], 0, 0, 0);
        sc1[j] = __builtin_amdgcn_mfma_f32_16x16x32_bf16(A1[ct], Bf, sc1[j], 0, 0, 0);
      }
    }
    proc_strip(s0, sc0, AT, quad, l15);
    proc_strip(s1, sc1, AT, quad, l15);
  }
}

// ---------------- Kernel: weighted GEMM + guide epilogue -------------------
// D[m][c] = sum_l attnT[m][l] * sam[c][l]; out[c][m] = (sam+D)*0.5*simw[m]
__global__ __launch_bounds__(256, 2) void k_weighted(const float* __restrict__ sam,
                                                     const unsigned short* __restrict__ attnT,
                                                     const float* __restrict__ simw,
                                                     float* __restrict__ out) {
  const int b = blockIdx.x, tid = threadIdx.x, lane = tid & 63, wv = tid >> 6;
  const int quad = lane >> 4, l15 = lane & 15;
  const float* __restrict__ S = sam + (size_t)b * 50176;
  const unsigned short* __restrict__ AT = attnT + (size_t)b * (208 * 224);
  float* __restrict__ O = out + (size_t)b * 50176;
  __shared__ unsigned short sB[128 * 232];
  __shared__ float s_w[196];

  if (tid < 196) s_w[tid] = simw[b * 196 + tid] * 0.5f;

  for (int h = 0; h < 2; ++h) {
    __syncthreads();
    for (int i = tid; i < 128 * 224; i += 256) {
      int c = i / 224, l = i - c * 224;
      float v = (l < 196) ? S[(h * 128 + c) * 196 + l] : 0.f;
      sB[c * 232 + l] = f2bf(v);
    }
    __syncthreads();
    f32x4 acc[13][2];
    const f32x4 z = {0.f, 0.f, 0.f, 0.f};
#pragma unroll
    for (int mb = 0; mb < 13; ++mb) { acc[mb][0] = z; acc[mb][1] = z; }
    for (int kt = 0; kt < 7; ++kt) {
      s16x8 B0 = *(const s16x8*)(sB + (wv * 32 + l15) * 232 + kt * 32 + quad * 8);
      s16x8 B1 = *(const s16x8*)(sB + (wv * 32 + 16 + l15) * 232 + kt * 32 + quad * 8);
#pragma unroll
      for (int mb = 0; mb < 13; ++mb) {
        s16x8 Af = *(const s16x8*)(AT + (mb * 16 + l15) * 224 + kt * 32 + quad * 8);
        acc[mb][0] = __builtin_amdgcn_mfma_f32_16x16x32_bf16(Af, B0, acc[mb][0], 0, 0, 0);
        acc[mb][1] = __builtin_amdgcn_mfma_f32_16x16x32_bf16(Af, B1, acc[mb][1], 0, 0, 0);
      }
    }
#pragma unroll
    for (int mb = 0; mb < 13; ++mb) {
      int m = mb * 16 + quad * 4;
      if (m < 196) {
        float4 w4 = *(const float4*)(s_w + m);
#pragma unroll
        for (int bj = 0; bj < 2; ++bj) {
          int c = h * 128 + wv * 32 + bj * 16 + l15;
          float4 s4 = *(const float4*)(S + c * 196 + m);
          float4 o4;
          o4.x = (s4.x + acc[mb][bj][0]) * w4.x;
          o4.y = (s4.y + acc[mb][bj][1]) * w4.y;
          o4.z = (s4.z + acc[mb][bj][2]) * w4.z;
          o4.w = (s4.w + acc[mb][bj][3]) * w4.w;
          *(float4*)(O + c * 196 + m) = o4;
        }
      }
    }
  }
}

// ---------------- Fallback fp32 fused attention (round-1 kernel) -----------
__global__ __launch_bounds__(256) void k_attn(const float* __restrict__ sam,
                                              const float* __restrict__ simw,
                                              float* __restrict__ out) {
  const int b = blockIdx.x;
  const int tid = threadIdx.x, lane = tid & 63, wv = tid >> 6;
  const float* __restrict__ S = sam + (size_t)b * (256 * 196);
  float* __restrict__ O = out + (size_t)b * (256 * 196);
  const float* __restrict__ SW = simw + b * 196;

  __shared__ float s_inv[196];
  __shared__ float s_max[196];
  __shared__ float s_rsum[196];
  __shared__ float bufS[28 * 197];
  __shared__ float bufT[256 * 29];

  for (int l = tid; l < 196; l += 256) {
    float ss = 0.f;
    for (int c = 0; c < 256; ++c) {
      float v = S[c * 196 + l];
      ss = fmaf(v, v, ss);
    }
    s_inv[l] = 1.0f / fmaxf(sqrtf(ss), 1e-12f);
  }

  for (int r0 = 0; r0 < 196; r0 += 28) {
    float acc[7][4];
#pragma unroll
    for (int i = 0; i < 7; ++i)
#pragma unroll
      for (int j = 0; j < 4; ++j) acc[i][j] = 0.f;
    const int lr = r0 + wv * 7;
    for (int ct = 0; ct < 8; ++ct) {
      __syncthreads();
      for (int i = tid; i < 32 * 196; i += 256)
        bufT[(i / 196) * 197 + (i % 196)] = S[ct * 32 * 196 + i];
      __syncthreads();
#pragma unroll 2
      for (int c = 0; c < 32; ++c) {
        const float* row = bufT + c * 197;
        float a[7];
#pragma unroll
        for (int i = 0; i < 7; ++i) a[i] = row[lr + i];
        float b0 = row[lane], b1 = row[lane + 64], b2 = row[lane + 128];
        float b3 = row[lane + 192];
#pragma unroll
        for (int i = 0; i < 7; ++i) {
          acc[i][0] = fmaf(a[i], b0, acc[i][0]);
          acc[i][1] = fmaf(a[i], b1, acc[i][1]);
          acc[i][2] = fmaf(a[i], b2, acc[i][2]);
          acc[i][3] = fmaf(a[i], b3, acc[i][3]);
        }
      }
    }
#pragma unroll
    for (int j = 0; j < 4; ++j) {
      int m = lane + 64 * j;
      if (m < 196) {
        float im = s_inv[m] * 0.0625f;
#pragma unroll
        for (int i = 0; i < 7; ++i)
          bufS[(wv * 7 + i) * 197 + m] = acc[i][j] * s_inv[lr + i] * im;
      }
    }
    __syncthreads();
#pragma unroll
    for (int i = 0; i < 7; ++i) {
      const int rl = wv * 7 + i;
      const float* sr = bufS + rl * 197;
      float v0 = sr[lane], v1 = sr[lane + 64], v2 = sr[lane + 128];
      bool g = (lane + 192) < 196;
      float v3 = g ? sr[lane + 192] : -1e30f;
      float mxv = fmaxf(fmaxf(v0, v1), fmaxf(v2, v3));
#pragma unroll
      for (int o = 32; o > 0; o >>= 1) mxv = fmaxf(mxv, __shfl_xor(mxv, o, 64));
      float sm = __expf(v0 - mxv) + __expf(v1 - mxv) + __expf(v2 - mxv) +
                 (g ? __expf(v3 - mxv) : 0.f);
      sm = wsum(sm);
      if (lane == 0) { s_max[r0 + rl] = mxv; s_rsum[r0 + rl] = 1.0f / sm; }
    }
  }
  __syncthreads();

  const int cg = tid >> 2, tq = tid & 3;
  for (int m0 = 0; m0 < 196; m0 += 28) {
    float acc[7][4];
#pragma unroll
    for (int i = 0; i < 7; ++i)
#pragma unroll
      for (int j = 0; j < 4; ++j) acc[i][j] = 0.f;
    const int mg = m0 + wv * 7;
    for (int ct = 0; ct < 8; ++ct) {
      __syncthreads();
      for (int i = tid; i < 32 * 196; i += 256)
        bufT[(i / 196) * 197 + (i % 196)] = S[ct * 32 * 196 + i];
      __syncthreads();
#pragma unroll 2
      for (int c = 0; c < 32; ++c) {
        const float* row = bufT + c * 197;
        float a[7];
#pragma unroll
        for (int i = 0; i < 7; ++i) a[i] = row[mg + i];
        float b0 = row[lane], b1 = row[lane + 64], b2 = row[lane + 128];
        float b3 = row[lane + 192];
#pragma unroll
        for (int i = 0; i < 7; ++i) {
          acc[i][0] = fmaf(a[i], b0, acc[i][0]);
          acc[i][1] = fmaf(a[i], b1, acc[i][1]);
          acc[i][2] = fmaf(a[i], b2, acc[i][2]);
          acc[i][3] = fmaf(a[i], b3, acc[i][3]);
        }
      }
    }
    __syncthreads();
#pragma unroll
    for (int j = 0; j < 4; ++j) {
      int l = lane + 64 * j;
      if (l < 196) {
        float il = s_inv[l] * 0.0625f;
        float mxl = s_max[l], rsl = s_rsum[l];
#pragma unroll
        for (int i = 0; i < 7; ++i) {
          float sc = acc[i][j] * s_inv[mg + i] * il;
          bufS[(wv * 7 + i) * 197 + l] = __expf(sc - mxl) * rsl;
        }
      }
    }
    __syncthreads();
    float w[4][7];
#pragma unroll
    for (int ii = 0; ii < 4; ++ii)
#pragma unroll
      for (int i = 0; i < 7; ++i) w[ii][i] = 0.f;
    for (int lt = 0; lt < 7; ++lt) {
      __syncthreads();
      for (int i = tid; i < 256 * 28; i += 256) {
        int c = i / 28, j = i - c * 28;
        bufT[c * 29 + j] = S[c * 196 + lt * 28 + j];
      }
      __syncthreads();
#pragma unroll 4
      for (int j = 0; j < 28; ++j) {
        float a0 = bufT[(cg * 4 + 0) * 29 + j];
        float a1 = bufT[(cg * 4 + 1) * 29 + j];
        float a2 = bufT[(cg * 4 + 2) * 29 + j];
        float a3 = bufT[(cg * 4 + 3) * 29 + j];
#pragma unroll
        for (int i = 0; i < 7; ++i) {
          float bv = bufS[(tq * 7 + i) * 197 + lt * 28 + j];
          w[0][i] = fmaf(a0, bv, w[0][i]);
          w[1][i] = fmaf(a1, bv, w[1][i]);
          w[2][i] = fmaf(a2, bv, w[2][i]);
          w[3][i] = fmaf(a3, bv, w[3][i]);
        }
      }
    }
#pragma unroll
    for (int i = 0; i < 7; ++i) {
      const int m = m0 + tq * 7 + i;
      float sw = SW[m] * 0.5f;
#pragma unroll
      for (int ii = 0; ii < 4; ++ii) {
        const int c = cg * 4 + ii;
        O[c * 196 + m] = (S[c * 196 + m] + w[ii][i]) * sw;
      }
    }
  }
}

// ---------------- Kernel: hierarchical norm (in-place) ---------------------
__global__ __launch_bounds__(256) void k_norm(float* __restrict__ x) {
  const int b = blockIdx.x, tid = threadIdx.x;
  float* __restrict__ X = x + (size_t)b * (256 * 196);
  __shared__ float s_mu[196], s_rs[196];
  __shared__ float s_rm[256], s_rc[256];
  __shared__ float tile[256 * 29];

  if (tid < 196) {
    float s = 0.f, q = 0.f;
    for (int c = 0; c < 256; ++c) {
      float v = X[c * 196 + tid];
      s += v;
      q = fmaf(v, v, q);
    }
    float mu = s * (1.0f / 256.0f);
    float var = q * (1.0f / 256.0f) - mu * mu;
    s_mu[tid] = mu;
    s_rs[tid] = rsqrtf(fmaxf(var, 0.f) + 1e-5f);
  }
  __syncthreads();

  float rs = 0.f, rq = 0.f;
  for (int m0 = 0; m0 < 196; m0 += 28) {
    __syncthreads();
    for (int i = tid; i < 256 * 28; i += 256) {
      int c = i / 28, j = i - c * 28;
      tile[c * 29 + j] = X[c * 196 + m0 + j];
    }
    __syncthreads();
#pragma unroll
    for (int j = 0; j < 28; ++j) {
      float y = (tile[tid * 29 + j] - s_mu[m0 + j]) * s_rs[m0 + j];
      rs += y;
      rq = fmaf(y, y, rq);
    }
  }
  float rm = rs * (1.0f / 196.0f);
  float var = (rq - 196.0f * rm * rm) * (1.0f / 195.0f);
  float sd = sqrtf(fmaxf(var, 0.f));
  s_rm[tid] = rm;
  s_rc[tid] = 1.0f / (sd + 1e-6f);
  __syncthreads();

  for (int i = tid; i < 256 * 196; i += 256) {
    int c = i / 196, m = i - c * 196;
    float y = (X[i] - s_mu[m]) * s_rs[m];
    X[i] = (y - s_rm[c]) * s_rc[c];
  }
}

extern "C" void kernel_launch(void* const* d_in, const int* in_sizes, int n_in,
                              void* d_out, int out_size, void* d_ws, size_t ws_size,
                              hipStream_t stream) {
  const float* img = (const float*)d_in[0];
  const float* txt = (const float*)d_in[1];
  const float* sam = (const float*)d_in[2];
  const float* Wsim = (const float*)d_in[3];
  const float* bsim = (const float*)d_in[4];
  float* out = (float*)d_out;

  const int B = in_sizes[0] / 512;  // 512

  const size_t simw_bytes = (((size_t)B * 196 * 4) + 511) & ~(size_t)511;
  const size_t samnT_bytes = (size_t)B * 208 * 256 * 2;
  const size_t attnT_bytes = (size_t)B * 208 * 224 * 2;
  const size_t need = simw_bytes + samnT_bytes + attnT_bytes;

  float* simw = (float*)d_ws;

  k_simw<<<B, 256, 0, stream>>>(img, txt, Wsim, bsim, simw);

  if (ws_size >= need) {
    unsigned short* samnT = (unsigned short*)((char*)d_ws + simw_bytes);
    unsigned short* attnT = (unsigned short*)((char*)d_ws + simw_bytes + samnT_bytes);
    k_prep<<<B, 256, 0, stream>>>(sam, samnT);
    k_scores<<<B, 256, 0, stream>>>(samnT, attnT);
    k_weighted<<<B, 256, 0, stream>>>(sam, attnT, simw, out);
  } else {
    k_attn<<<B, 256, 0, stream>>>(sam, simw, out);
  }
  k_norm<<<B, 256, 0, stream>>>(out);
}

// Round 3
// 754.067 us; speedup vs baseline: 1.8849x; 1.0857x over previous
//
#include <hip/hip_runtime.h>
#include <math.h>

// B=512, C=256, H=W=14 -> L=196 (pad 208 rows / 224 K), D=512

typedef float f32x4 __attribute__((ext_vector_type(4)));
typedef short s16x8 __attribute__((ext_vector_type(8)));

__device__ __forceinline__ float wsum(float v) {
#pragma unroll
  for (int o = 32; o > 0; o >>= 1) v += __shfl_xor(v, o, 64);
  return v;
}

__device__ __forceinline__ unsigned short f2bf(float f) {
  unsigned int u = __float_as_uint(f);
  u += 0x7FFFu + ((u >> 16) & 1u);  // RNE
  return (unsigned short)(u >> 16);
}

// ---------------- Kernel: similarity weights -------------------------------
__global__ __launch_bounds__(256) void k_simw(const float* __restrict__ img,
                                              const float* __restrict__ txt,
                                              const float* __restrict__ Wsim,
                                              const float* __restrict__ bsim,
                                              float* __restrict__ simw) {
  const int b = blockIdx.x, tid = threadIdx.x, lane = tid & 63, wv = tid >> 6;
  __shared__ float s_img[512];
  __shared__ float s_part[3][4];

  float i0 = img[b * 512 + tid], i1 = img[b * 512 + 256 + tid];
  float t0 = txt[b * 512 + tid], t1 = txt[b * 512 + 256 + tid];
  float ssi = wsum(i0 * i0 + i1 * i1);
  float sst = wsum(t0 * t0 + t1 * t1);
  float dd = wsum(i0 * t0 + i1 * t1);
  if (lane == 0) { s_part[0][wv] = ssi; s_part[1][wv] = sst; s_part[2][wv] = dd; }
  __syncthreads();
  float ni = fmaxf(sqrtf(s_part[0][0] + s_part[0][1] + s_part[0][2] + s_part[0][3]), 1e-12f);
  float nt = fmaxf(sqrtf(s_part[1][0] + s_part[1][1] + s_part[1][2] + s_part[1][3]), 1e-12f);
  float dot = s_part[2][0] + s_part[2][1] + s_part[2][2] + s_part[2][3];
  float cross = dot / (ni * nt);
  float rni = 1.0f / ni;
  s_img[tid] = i0 * rni;
  s_img[tid + 256] = i1 * rni;
  __syncthreads();

  for (int l = wv; l < 196; l += 4) {
    const float* wr = Wsim + (size_t)l * 512;
    float p = 0.f;
#pragma unroll
    for (int k = 0; k < 8; ++k) p = fmaf(s_img[lane + 64 * k], wr[lane + 64 * k], p);
    p = wsum(p);
    if (lane == 0) {
      float z = p + bsim[l];
      float sg = 1.0f / (1.0f + __expf(-z));
      simw[b * 196 + l] = cross * sg * 0.1f;
    }
  }
}

// ---------------- Kernel: prep — normalized transposed bf16 samnT ----------
// samnT[b][l][c] = sam[b][c][l] / max(||col l||, eps), rows l=196..207 zero.
__global__ __launch_bounds__(256) void k_prep(const float* __restrict__ sam,
                                              unsigned short* __restrict__ samnT) {
  const int b = blockIdx.x, tid = threadIdx.x, lane = tid & 63, wv = tid >> 6;
  const float* __restrict__ S = sam + (size_t)b * 50176;
  unsigned short* __restrict__ NT = samnT + (size_t)b * (208 * 256);
  __shared__ float s_inv[196];
  __shared__ float T[64 * 197];

  if (tid < 196) {
    float ss = 0.f;
    for (int c = 0; c < 256; ++c) {
      float v = S[c * 196 + tid];
      ss = fmaf(v, v, ss);
    }
    s_inv[tid] = 1.0f / fmaxf(sqrtf(ss), 1e-12f);
  }
  // zero pad rows l=196..207 (12*256 ushort = 1536 dwords)
  for (int i = tid; i < 1536; i += 256) ((unsigned int*)(NT + 196 * 256))[i] = 0;
  __syncthreads();

  for (int c0 = 0; c0 < 256; c0 += 64) {
    for (int cr = wv; cr < 64; cr += 4) {
      const float* Sr = S + (c0 + cr) * 196;
      float* Tr = T + cr * 197;
      Tr[lane] = Sr[lane] * s_inv[lane];
      Tr[lane + 64] = Sr[lane + 64] * s_inv[lane + 64];
      Tr[lane + 128] = Sr[lane + 128] * s_inv[lane + 128];
      if (lane < 4) Tr[lane + 192] = Sr[lane + 192] * s_inv[lane + 192];
    }
    __syncthreads();
    const int lrow = tid >> 3, cch = tid & 7;
    for (int l0 = 0; l0 < 196; l0 += 32) {
      int l = l0 + lrow;
      if (l < 196) {
        const float* Tc = T + (cch * 8) * 197 + l;
        unsigned short r[8];
#pragma unroll
        for (int k = 0; k < 8; ++k) r[k] = f2bf(Tc[k * 197]);
        uint4 o;
        o.x = r[0] | ((unsigned int)r[1] << 16);
        o.y = r[2] | ((unsigned int)r[3] << 16);
        o.z = r[4] | ((unsigned int)r[5] << 16);
        o.w = r[6] | ((unsigned int)r[7] << 16);
        *(uint4*)(NT + l * 256 + c0 + cch * 8) = o;
      }
    }
    __syncthreads();
  }
}

// ---------------- Kernel: scores GEMM + softmax -> attnT bf16 --------------
// One block per batch. NT staged into LDS in two 128-wide K-halves.
__device__ __forceinline__ void proc_strip(int s, f32x4* sc, unsigned short* AT,
                                           int quad, int l15) {
  const bool mval12 = (192 + l15) < 196;  // j==12 column validity
  float mx[4], rs[4];
#pragma unroll
  for (int r = 0; r < 4; ++r) {
    float m = -3e38f;
#pragma unroll
    for (int j = 0; j < 13; ++j) {
      float v = sc[j][r];
      if (j == 12 && !mval12) v = -3e38f;
      m = fmaxf(m, v);
    }
#pragma unroll
    for (int o = 1; o < 16; o <<= 1) m = fmaxf(m, __shfl_xor(m, o, 64));
    float s_ = 0.f;
#pragma unroll
    for (int j = 0; j < 13; ++j) {
      float e = __expf(sc[j][r] - m);
      if (j == 12 && !mval12) e = 0.f;
      s_ += e;
    }
#pragma unroll
    for (int o = 1; o < 16; o <<= 1) s_ += __shfl_xor(s_, o, 64);
    mx[r] = m;
    rs[r] = 1.0f / s_;
  }
  const int lb = s * 16 + quad * 4;
#pragma unroll
  for (int j = 0; j < 13; ++j) {
    unsigned short u[4];
#pragma unroll
    for (int r = 0; r < 4; ++r) {
      float a = __expf(sc[j][r] - mx[r]) * rs[r];
      if (lb + r >= 196) a = 0.f;  // K-padding rows of attn must be zero
      u[r] = f2bf(a);
    }
    uint2 o2;
    o2.x = u[0] | ((unsigned int)u[1] << 16);
    o2.y = u[2] | ((unsigned int)u[3] << 16);
    *(uint2*)(AT + (j * 16 + l15) * 224 + lb) = o2;
  }
}

__global__ __launch_bounds__(256, 2) void k_scores(const unsigned short* __restrict__ samnT,
                                                   unsigned short* __restrict__ attnT) {
  const int b = blockIdx.x, tid = threadIdx.x, lane = tid & 63, wv = tid >> 6;
  const int quad = lane >> 4, l15 = lane & 15;
  const unsigned short* __restrict__ NT = samnT + (size_t)b * (208 * 256);
  unsigned short* __restrict__ AT = attnT + (size_t)b * (208 * 224);
  __shared__ unsigned short sN[208 * 136];  // 56.6 KB, one 128-wide K half

  // zero attnT[:, 208..223]
  for (int i = tid; i < 208 * 8; i += 256) {
    int m = i >> 3, k = i & 7;
    ((unsigned int*)(AT + m * 224 + 208))[k] = 0;
  }

  for (int pr = 0; pr < 2; ++pr) {
    const int p = wv + 4 * pr;  // pair index; p>=7 -> this wave idles in MFMA
    const int s0 = 2 * p, s1 = (2 * p + 1 < 13) ? (2 * p + 1) : 12;
    f32x4 sc0[13], sc1[13];
    const f32x4 z = {0.f, 0.f, 0.f, 0.f};
#pragma unroll
    for (int j = 0; j < 13; ++j) { sc0[j] = z; sc1[j] = z; }
    for (int h = 0; h < 2; ++h) {
      __syncthreads();
      for (int i = tid; i < 208 * 16; i += 256) {
        int l = i >> 4, cc = i & 15;
        *(uint4*)(sN + l * 136 + cc * 8) = *(const uint4*)(NT + l * 256 + h * 128 + cc * 8);
      }
      __syncthreads();
      if (p < 7) {
        s16x8 A0[4], A1[4];
#pragma unroll
        for (int ct = 0; ct < 4; ++ct) {
          A0[ct] = *(const s16x8*)(sN + (s0 * 16 + l15) * 136 + ct * 32 + quad * 8);
          A1[ct] = *(const s16x8*)(sN + (s1 * 16 + l15) * 136 + ct * 32 + quad * 8);
        }
#pragma unroll
        for (int j = 0; j < 13; ++j) {
#pragma unroll
          for (int ct = 0; ct < 4; ++ct) {
            s16x8 Bf = *(const s16x8*)(sN + (j * 16 + l15) * 136 + ct * 32 + quad * 8);
            sc0[j] = __builtin_amdgcn_mfma_f32_16x16x32_bf16(A0[ct], Bf, sc0[j], 0, 0, 0);
            sc1[j] = __builtin_amdgcn_mfma_f32_16x16x32_bf16(A1[ct], Bf, sc1[j], 0, 0, 0);
          }
        }
      }
    }
    if (p < 7) {
      proc_strip(s0, sc0, AT, quad, l15);
      proc_strip(s1, sc1, AT, quad, l15);
    }
  }
}

// ---------------- Kernel: weighted GEMM + guide epilogue -------------------
// D[c][m] = sum_l sam[c][l] * attn[l][m]; out[c][m] = (sam+D)*0.5*simw[m]
// A = sam c-rows (LDS bf16), B = attnT m-rows (global). D cols = m -> coalesced.
__global__ __launch_bounds__(256, 2) void k_weighted(const float* __restrict__ sam,
                                                     const unsigned short* __restrict__ attnT,
                                                     const float* __restrict__ simw,
                                                     float* __restrict__ out) {
  const int b = blockIdx.x, tid = threadIdx.x, lane = tid & 63, wv = tid >> 6;
  const int quad = lane >> 4, l15 = lane & 15;
  const float* __restrict__ S = sam + (size_t)b * 50176;
  const unsigned short* __restrict__ AT = attnT + (size_t)b * (208 * 224);
  float* __restrict__ O = out + (size_t)b * 50176;
  __shared__ unsigned short sB[128 * 232];
  __shared__ float s_w[196];

  if (tid < 196) s_w[tid] = simw[b * 196 + tid] * 0.5f;

  for (int h = 0; h < 2; ++h) {
    __syncthreads();
    for (int i = tid; i < 128 * 224; i += 256) {
      int c = i / 224, l = i - c * 224;
      float v = (l < 196) ? S[(h * 128 + c) * 196 + l] : 0.f;
      sB[c * 232 + l] = f2bf(v);
    }
    __syncthreads();
    f32x4 acc[13][2];
    const f32x4 z = {0.f, 0.f, 0.f, 0.f};
#pragma unroll
    for (int mb = 0; mb < 13; ++mb) { acc[mb][0] = z; acc[mb][1] = z; }
    for (int kt = 0; kt < 7; ++kt) {
      s16x8 A0 = *(const s16x8*)(sB + (wv * 32 + l15) * 232 + kt * 32 + quad * 8);
      s16x8 A1 = *(const s16x8*)(sB + (wv * 32 + 16 + l15) * 232 + kt * 32 + quad * 8);
      s16x8 Bf[13];
#pragma unroll
      for (int mb = 0; mb < 13; ++mb)
        Bf[mb] = *(const s16x8*)(AT + (mb * 16 + l15) * 224 + kt * 32 + quad * 8);
#pragma unroll
      for (int mb = 0; mb < 13; ++mb) {
        acc[mb][0] = __builtin_amdgcn_mfma_f32_16x16x32_bf16(A0, Bf[mb], acc[mb][0], 0, 0, 0);
        acc[mb][1] = __builtin_amdgcn_mfma_f32_16x16x32_bf16(A1, Bf[mb], acc[mb][1], 0, 0, 0);
      }
    }
    // epilogue: D row = c (quad*4+r within 16-tile), col = m (l15, contiguous)
#pragma unroll
    for (int mb = 0; mb < 13; ++mb) {
      const int m = mb * 16 + l15;
      if (m < 196) {
        const float w = s_w[m];
#pragma unroll
        for (int bj = 0; bj < 2; ++bj) {
#pragma unroll
          for (int r = 0; r < 4; ++r) {
            const int c = h * 128 + wv * 32 + bj * 16 + quad * 4 + r;
            O[c * 196 + m] = (S[c * 196 + m] + acc[mb][bj][r]) * w;
          }
        }
      }
    }
  }
}

// ---------------- Fallback fp32 fused attention ----------------------------
__global__ __launch_bounds__(256) void k_attn(const float* __restrict__ sam,
                                              const float* __restrict__ simw,
                                              float* __restrict__ out) {
  const int b = blockIdx.x;
  const int tid = threadIdx.x, lane = tid & 63, wv = tid >> 6;
  const float* __restrict__ S = sam + (size_t)b * (256 * 196);
  float* __restrict__ O = out + (size_t)b * (256 * 196);
  const float* __restrict__ SW = simw + b * 196;

  __shared__ float s_inv[196];
  __shared__ float s_max[196];
  __shared__ float s_rsum[196];
  __shared__ float bufS[28 * 197];
  __shared__ float bufT[256 * 29];

  for (int l = tid; l < 196; l += 256) {
    float ss = 0.f;
    for (int c = 0; c < 256; ++c) {
      float v = S[c * 196 + l];
      ss = fmaf(v, v, ss);
    }
    s_inv[l] = 1.0f / fmaxf(sqrtf(ss), 1e-12f);
  }

  for (int r0 = 0; r0 < 196; r0 += 28) {
    float acc[7][4];
#pragma unroll
    for (int i = 0; i < 7; ++i)
#pragma unroll
      for (int j = 0; j < 4; ++j) acc[i][j] = 0.f;
    const int lr = r0 + wv * 7;
    for (int ct = 0; ct < 8; ++ct) {
      __syncthreads();
      for (int i = tid; i < 32 * 196; i += 256)
        bufT[(i / 196) * 197 + (i % 196)] = S[ct * 32 * 196 + i];
      __syncthreads();
#pragma unroll 2
      for (int c = 0; c < 32; ++c) {
        const float* row = bufT + c * 197;
        float a[7];
#pragma unroll
        for (int i = 0; i < 7; ++i) a[i] = row[lr + i];
        float b0 = row[lane], b1 = row[lane + 64], b2 = row[lane + 128];
        float b3 = row[lane + 192];
#pragma unroll
        for (int i = 0; i < 7; ++i) {
          acc[i][0] = fmaf(a[i], b0, acc[i][0]);
          acc[i][1] = fmaf(a[i], b1, acc[i][1]);
          acc[i][2] = fmaf(a[i], b2, acc[i][2]);
          acc[i][3] = fmaf(a[i], b3, acc[i][3]);
        }
      }
    }
#pragma unroll
    for (int j = 0; j < 4; ++j) {
      int m = lane + 64 * j;
      if (m < 196) {
        float im = s_inv[m] * 0.0625f;
#pragma unroll
        for (int i = 0; i < 7; ++i)
          bufS[(wv * 7 + i) * 197 + m] = acc[i][j] * s_inv[lr + i] * im;
      }
    }
    __syncthreads();
#pragma unroll
    for (int i = 0; i < 7; ++i) {
      const int rl = wv * 7 + i;
      const float* sr = bufS + rl * 197;
      float v0 = sr[lane], v1 = sr[lane + 64], v2 = sr[lane + 128];
      bool g = (lane + 192) < 196;
      float v3 = g ? sr[lane + 192] : -1e30f;
      float mxv = fmaxf(fmaxf(v0, v1), fmaxf(v2, v3));
#pragma unroll
      for (int o = 32; o > 0; o >>= 1) mxv = fmaxf(mxv, __shfl_xor(mxv, o, 64));
      float sm = __expf(v0 - mxv) + __expf(v1 - mxv) + __expf(v2 - mxv) +
                 (g ? __expf(v3 - mxv) : 0.f);
      sm = wsum(sm);
      if (lane == 0) { s_max[r0 + rl] = mxv; s_rsum[r0 + rl] = 1.0f / sm; }
    }
  }
  __syncthreads();

  const int cg = tid >> 2, tq = tid & 3;
  for (int m0 = 0; m0 < 196; m0 += 28) {
    float acc[7][4];
#pragma unroll
    for (int i = 0; i < 7; ++i)
#pragma unroll
      for (int j = 0; j < 4; ++j) acc[i][j] = 0.f;
    const int mg = m0 + wv * 7;
    for (int ct = 0; ct < 8; ++ct) {
      __syncthreads();
      for (int i = tid; i < 32 * 196; i += 256)
        bufT[(i / 196) * 197 + (i % 196)] = S[ct * 32 * 196 + i];
      __syncthreads();
#pragma unroll 2
      for (int c = 0; c < 32; ++c) {
        const float* row = bufT + c * 197;
        float a[7];
#pragma unroll
        for (int i = 0; i < 7; ++i) a[i] = row[mg + i];
        float b0 = row[lane], b1 = row[lane + 64], b2 = row[lane + 128];
        float b3 = row[lane + 192];
#pragma unroll
        for (int i = 0; i < 7; ++i) {
          acc[i][0] = fmaf(a[i], b0, acc[i][0]);
          acc[i][1] = fmaf(a[i], b1, acc[i][1]);
          acc[i][2] = fmaf(a[i], b2, acc[i][2]);
          acc[i][3] = fmaf(a[i], b3, acc[i][3]);
        }
      }
    }
    __syncthreads();
#pragma unroll
    for (int j = 0; j < 4; ++j) {
      int l = lane + 64 * j;
      if (l < 196) {
        float il = s_inv[l] * 0.0625f;
        float mxl = s_max[l], rsl = s_rsum[l];
#pragma unroll
        for (int i = 0; i < 7; ++i) {
          float sc = acc[i][j] * s_inv[mg + i] * il;
          bufS[(wv * 7 + i) * 197 + l] = __expf(sc - mxl) * rsl;
        }
      }
    }
    __syncthreads();
    float w[4][7];
#pragma unroll
    for (int ii = 0; ii < 4; ++ii)
#pragma unroll
      for (int i = 0; i < 7; ++i) w[ii][i] = 0.f;
    for (int lt = 0; lt < 7; ++lt) {
      __syncthreads();
      for (int i = tid; i < 256 * 28; i += 256) {
        int c = i / 28, j = i - c * 28;
        bufT[c * 29 + j] = S[c * 196 + lt * 28 + j];
      }
      __syncthreads();
#pragma unroll 4
      for (int j = 0; j < 28; ++j) {
        float a0 = bufT[(cg * 4 + 0) * 29 + j];
        float a1 = bufT[(cg * 4 + 1) * 29 + j];
        float a2 = bufT[(cg * 4 + 2) * 29 + j];
        float a3 = bufT[(cg * 4 + 3) * 29 + j];
#pragma unroll
        for (int i = 0; i < 7; ++i) {
          float bv = bufS[(tq * 7 + i) * 197 + lt * 28 + j];
          w[0][i] = fmaf(a0, bv, w[0][i]);
          w[1][i] = fmaf(a1, bv, w[1][i]);
          w[2][i] = fmaf(a2, bv, w[2][i]);
          w[3][i] = fmaf(a3, bv, w[3][i]);
        }
      }
    }
#pragma unroll
    for (int i = 0; i < 7; ++i) {
      const int m = m0 + tq * 7 + i;
      float sw = SW[m] * 0.5f;
#pragma unroll
      for (int ii = 0; ii < 4; ++ii) {
        const int c = cg * 4 + ii;
        O[c * 196 + m] = (S[c * 196 + m] + w[ii][i]) * sw;
      }
    }
  }
}

// ---------------- Kernel: hierarchical norm (in-place) ---------------------
__global__ __launch_bounds__(256) void k_norm(float* __restrict__ x) {
  const int b = blockIdx.x, tid = threadIdx.x;
  float* __restrict__ X = x + (size_t)b * (256 * 196);
  __shared__ float s_mu[196], s_rs[196];
  __shared__ float s_rm[256], s_rc[256];
  __shared__ float tile[256 * 29];

  if (tid < 196) {
    float s = 0.f, q = 0.f;
    for (int c = 0; c < 256; ++c) {
      float v = X[c * 196 + tid];
      s += v;
      q = fmaf(v, v, q);
    }
    float mu = s * (1.0f / 256.0f);
    float var = q * (1.0f / 256.0f) - mu * mu;
    s_mu[tid] = mu;
    s_rs[tid] = rsqrtf(fmaxf(var, 0.f) + 1e-5f);
  }
  __syncthreads();

  float rs = 0.f, rq = 0.f;
  for (int m0 = 0; m0 < 196; m0 += 28) {
    __syncthreads();
    for (int i = tid; i < 256 * 28; i += 256) {
      int c = i / 28, j = i - c * 28;
      tile[c * 29 + j] = X[c * 196 + m0 + j];
    }
    __syncthreads();
#pragma unroll
    for (int j = 0; j < 28; ++j) {
      float y = (tile[tid * 29 + j] - s_mu[m0 + j]) * s_rs[m0 + j];
      rs += y;
      rq = fmaf(y, y, rq);
    }
  }
  float rm = rs * (1.0f / 196.0f);
  float var = (rq - 196.0f * rm * rm) * (1.0f / 195.0f);
  float sd = sqrtf(fmaxf(var, 0.f));
  s_rm[tid] = rm;
  s_rc[tid] = 1.0f / (sd + 1e-6f);
  __syncthreads();

  for (int i = tid; i < 256 * 196; i += 256) {
    int c = i / 196, m = i - c * 196;
    float y = (X[i] - s_mu[m]) * s_rs[m];
    X[i] = (y - s_rm[c]) * s_rc[c];
  }
}

extern "C" void kernel_launch(void* const* d_in, const int* in_sizes, int n_in,
                              void* d_out, int out_size, void* d_ws, size_t ws_size,
                              hipStream_t stream) {
  const float* img = (const float*)d_in[0];
  const float* txt = (const float*)d_in[1];
  const float* sam = (const float*)d_in[2];
  const float* Wsim = (const float*)d_in[3];
  const float* bsim = (const float*)d_in[4];
  float* out = (float*)d_out;

  const int B = in_sizes[0] / 512;  // 512

  const size_t simw_bytes = (((size_t)B * 196 * 4) + 511) & ~(size_t)511;
  const size_t samnT_bytes = (size_t)B * 208 * 256 * 2;
  const size_t attnT_bytes = (size_t)B * 208 * 224 * 2;
  const size_t need = simw_bytes + samnT_bytes + attnT_bytes;

  float* simw = (float*)d_ws;

  k_simw<<<B, 256, 0, stream>>>(img, txt, Wsim, bsim, simw);

  if (ws_size >= need) {
    unsigned short* samnT = (unsigned short*)((char*)d_ws + simw_bytes);
    unsigned short* attnT = (unsigned short*)((char*)d_ws + simw_bytes + samnT_bytes);
    k_prep<<<B, 256, 0, stream>>>(sam, samnT);
    k_scores<<<B, 256, 0, stream>>>(samnT, attnT);
    k_weighted<<<B, 256, 0, stream>>>(sam, attnT, simw, out);
  } else {
    k_attn<<<B, 256, 0, stream>>>(sam, simw, out);
  }
  k_norm<<<B, 256, 0, stream>>>(out);
}